// Round 1
// baseline (1667.536 us; speedup 1.0000x reference)
//
#include <hip/hip_runtime.h>

#define N_    64
#define CIN_  192
#define T_    256
#define V_    25
#define K_    3
#define COUT_ 64
#define OC_   192   // K*COUT
#define SS_   5
#define VP_   28    // V padded to multiple of 4 for float4

#define OUT_OFF_A (N_*COUT_*T_*V_)          // 26214400
#define OUT_OFF_G (OUT_OFF_A + K_*V_*V_)    // 26216275
#define TT_   4

// ---------------- kernel 1: transpose Wc (o,c) -> (c,o) for coalesced loads ----
__global__ __launch_bounds__(256) void transpose_wc(const float* __restrict__ Wc,
                                                    float* __restrict__ WcT) {
    int idx = blockIdx.x * 256 + threadIdx.x;
    if (idx < OC_ * CIN_) {
        int o = idx / CIN_, c = idx - o * CIN_;
        WcT[c * OC_ + o] = Wc[idx];
    }
}

// ---------------- kernel 2: xsum[n,c,v] = sum_t x[n,c,t,v] ---------------------
__global__ __launch_bounds__(256) void reduce_x(const float* __restrict__ x,
                                                float* __restrict__ xsum) {
    int i = blockIdx.x * 256 + threadIdx.x;
    if (i >= N_ * CIN_ * V_) return;
    int n = i / (CIN_ * V_);
    int r = i - n * (CIN_ * V_);
    int c = r / V_, v = r - c * V_;
    const float* p = x + ((size_t)(n * CIN_ + c)) * (T_ * V_) + v;
    float acc = 0.f;
#pragma unroll 8
    for (int t = 0; t < T_; ++t) acc += p[t * V_];
    xsum[i] = acc;
}

// ---------------- kernel 3: fused y = Wc@x + bc, then out = sum_{k,v} y*A ------
__global__ __launch_bounds__(192) void main_fused(const float* __restrict__ x,
                                                  const float* __restrict__ WcT,
                                                  const float* __restrict__ bc,
                                                  const float* __restrict__ A,
                                                  float* __restrict__ out) {
    __shared__ float xl[CIN_ * VP_];   // 5376 floats
    __shared__ float yl[OC_ * VP_];    // 5376 floats
    __shared__ float Al[K_ * V_ * V_]; // 1875 floats
    const int tid = threadIdx.x;
    const int bid = blockIdx.x;
    const int n  = bid / (T_ / TT_);
    const int t0 = (bid - n * (T_ / TT_)) * TT_;

    for (int idx = tid; idx < K_ * V_ * V_; idx += 192) Al[idx] = A[idx];
    const float bcv = bc[tid];  // blockDim == OC_ == 192
    const float* xn = x + (size_t)n * CIN_ * T_ * V_;

    for (int tt = 0; tt < TT_; ++tt) {
        const int t = t0 + tt;
        __syncthreads();
        // stage x[n,:,t,:] into LDS (padded stride VP_)
        for (int idx = tid; idx < CIN_ * V_; idx += 192) {
            int c = idx / V_, v = idx - c * V_;
            xl[c * VP_ + v] = xn[c * (T_ * V_) + t * V_ + v];
        }
        __syncthreads();
        // y[o, 0..24]: thread owns o = tid
        float4 acc[7];
#pragma unroll
        for (int j = 0; j < 7; ++j) acc[j] = make_float4(bcv, bcv, bcv, bcv);
        for (int c = 0; c < CIN_; ++c) {
            float w = WcT[c * OC_ + tid];          // coalesced, L2-resident
            const float4* xv = (const float4*)&xl[c * VP_];
#pragma unroll
            for (int j = 0; j < 7; ++j) {
                float4 xx = xv[j];                 // wave-uniform -> LDS broadcast
                acc[j].x += w * xx.x; acc[j].y += w * xx.y;
                acc[j].z += w * xx.z; acc[j].w += w * xx.w;
            }
        }
        float4* yo = (float4*)&yl[tid * VP_];
#pragma unroll
        for (int j = 0; j < 7; ++j) yo[j] = acc[j];
        __syncthreads();
        // out[n,cc,t,w] = sum_k sum_v y[k*64+cc, v] * A[k,v,w]
        for (int idx = tid; idx < COUT_ * V_; idx += 192) {
            int cc = idx / V_, w = idx - cc * V_;
            float a = 0.f;
#pragma unroll
            for (int k = 0; k < K_; ++k) {
                const float* yrow = &yl[(k * COUT_ + cc) * VP_];
                const float* arow = &Al[k * V_ * V_ + w];
#pragma unroll
                for (int v = 0; v < V_; ++v) a += yrow[v] * arow[v * V_];
            }
            out[(((size_t)n * COUT_ + cc) * T_ + t) * V_ + w] = a;
        }
    }
}

// ---------------- kernel 4: epilogue per n: ybar -> x1m/x2m -> sem -> graphs ---
__global__ __launch_bounds__(256) void epilogue(const float* __restrict__ xsum,
                                                const float* __restrict__ Wc,
                                                const float* __restrict__ bc,
                                                const float* __restrict__ W1,
                                                const float* __restrict__ b1,
                                                const float* __restrict__ W2,
                                                const float* __restrict__ b2,
                                                const int* __restrict__ node_type,
                                                const float* __restrict__ A,
                                                float* __restrict__ out) {
    __shared__ float xl[CIN_ * V_];          // 4800
    __shared__ float ylb[OC_ * V_];          // 4800
    __shared__ float x1l[SS_ * COUT_ * V_];  // 8000
    __shared__ float x2l[SS_ * COUT_ * V_];  // 8000
    __shared__ float sem[SS_ * COUT_];       // 320
    const int tid = threadIdx.x;
    const int n = blockIdx.x;

    if (n == 0) {  // A passthrough
        for (int idx = tid; idx < K_ * V_ * V_; idx += 256)
            out[OUT_OFF_A + idx] = A[idx];
    }
    for (int idx = tid; idx < CIN_ * V_; idx += 256)
        xl[idx] = xsum[n * (CIN_ * V_) + idx] * (1.0f / T_);
    __syncthreads();
    // ybar[o,v] = bc[o] + sum_c Wc[o,c] * xbar[c,v]
    for (int idx = tid; idx < OC_ * V_; idx += 256) {
        int o = idx / V_, v = idx - o * V_;
        float a = bc[o];
        for (int c = 0; c < CIN_; ++c) a += Wc[o * CIN_ + c] * xl[c * V_ + v];
        ylb[idx] = a;
    }
    __syncthreads();
    // x1m/x2m[j,v] = b[j] + sum_o W[j,o] * ybar[o,v]
    for (int idx = tid; idx < SS_ * COUT_ * V_; idx += 256) {
        int j = idx / V_, v = idx - j * V_;
        float a1 = b1[j], a2 = b2[j];
        for (int o = 0; o < OC_; ++o) {
            float yv = ylb[o * V_ + v];
            a1 += W1[j * OC_ + o] * yv;
            a2 += W2[j * OC_ + o] * yv;
        }
        x1l[idx] = a1; x2l[idx] = a2;
    }
    __syncthreads();
    // sem[s,c] = masked mean over v
    for (int idx = tid; idx < SS_ * COUT_; idx += 256) {
        int s = idx / COUT_;
        float sum = 0.f, cnt = 0.f;
        for (int v = 0; v < V_; ++v) {
            if (node_type[v] == s) { sum += x1l[idx * V_ + v]; cnt += 1.f; }
        }
        sem[idx] = sum / cnt;
    }
    __syncthreads();
    // graphs[n,s,c,v] = sem[s,c] - x2m[s,c,v]
    for (int idx = tid; idx < SS_ * COUT_ * V_; idx += 256) {
        int j = idx / V_;
        out[OUT_OFF_G + (size_t)n * (SS_ * COUT_ * V_) + idx] = sem[j] - x2l[idx];
    }
}

extern "C" void kernel_launch(void* const* d_in, const int* in_sizes, int n_in,
                              void* d_out, int out_size, void* d_ws, size_t ws_size,
                              hipStream_t stream) {
    const float* x         = (const float*)d_in[0];
    const float* A         = (const float*)d_in[1];
    const int*   node_type = (const int*)d_in[2];
    const float* Wc        = (const float*)d_in[3];
    const float* bc        = (const float*)d_in[4];
    const float* W1        = (const float*)d_in[5];
    const float* b1        = (const float*)d_in[6];
    const float* W2        = (const float*)d_in[7];
    const float* b2        = (const float*)d_in[8];
    float* out = (float*)d_out;

    float* WcT  = (float*)d_ws;            // 36864 floats
    float* xsum = WcT + OC_ * CIN_;        // 307200 floats  (total ws ~1.4 MB)

    hipLaunchKernelGGL(transpose_wc, dim3((OC_ * CIN_ + 255) / 256), dim3(256), 0, stream, Wc, WcT);
    hipLaunchKernelGGL(reduce_x, dim3((N_ * CIN_ * V_ + 255) / 256), dim3(256), 0, stream, x, xsum);
    hipLaunchKernelGGL(main_fused, dim3(N_ * (T_ / TT_)), dim3(192), 0, stream, x, WcT, bc, A, out);
    hipLaunchKernelGGL(epilogue, dim3(N_), dim3(256), 0, stream, xsum, Wc, bc, W1, b1, W2, b2, node_type, A, out);
}

// Round 2
// 720.759 us; speedup vs baseline: 2.3136x; 2.3136x over previous
//
#include <hip/hip_runtime.h>

#define N_    64
#define CIN_  192
#define T_    256
#define V_    25
#define K_    3
#define COUT_ 64
#define OC_   192
#define SS_   5

#define OUT_OFF_A (N_*COUT_*T_*V_)          // 26214400
#define OUT_OFF_G (OUT_OFF_A + K_*V_*V_)    // 26216275

// fused-kernel tiling
#define TCH   4
#define NCOLS 100            // TCH*V_
#define XB_STRIDE 200        // shorts per XB row (192 + 8 pad); 400 B, 16B-aligned, 2-way banks
#define YB_STRIDE 104        // shorts per YB row (75 -> pad 96 -> 104); 208 B, 16B-aligned
#define UNION_SHORTS 26624   // max(112*200=22400, 256*104=26624)

typedef __attribute__((ext_vector_type(8))) short short8;
typedef __attribute__((ext_vector_type(4))) float float4v;

__device__ inline unsigned bf16r(float f) {            // fp32 -> bf16 RNE
    unsigned u = __float_as_uint(f);
    return (u + 0x7fffu + ((u >> 16) & 1u)) >> 16;
}

// ---------- prep: WcB (bf16), A2T (Acat^T, bf16, zero-padded), A passthrough ----
__global__ __launch_bounds__(256) void prep(const float* __restrict__ Wc,
                                            const float* __restrict__ A,
                                            short* __restrict__ WcB,
                                            short* __restrict__ A2T,
                                            float* __restrict__ out) {
    int idx = blockIdx.x * 256 + threadIdx.x;
    if (idx < OC_ * CIN_) WcB[idx] = (short)bf16r(Wc[idx]);
    if (idx < 32 * YB_STRIDE) {           // A2T[w][kk], kk = k*25+v, zeros elsewhere
        int w = idx / YB_STRIDE, kk = idx - w * YB_STRIDE;
        short val = 0;
        if (w < V_ && kk < K_ * V_) {
            int k = kk / V_, v = kk - k * V_;
            val = (short)bf16r(A[k * V_ * V_ + v * V_ + w]);
        }
        A2T[idx] = val;
    }
    if (idx < K_ * V_ * V_) out[OUT_OFF_A + idx] = A[idx];
}

// ---------- reduce: xsum[n,c,v] = sum_t x[n,c,t,v]; one wave per (n,c) ----------
__global__ __launch_bounds__(256) void reduce_x(const float* __restrict__ x,
                                                float* __restrict__ xsum) {
    int lane = threadIdx.x & 63;
    int id = blockIdx.x * 4 + (threadIdx.x >> 6);    // (n*192 + c)
    const float* p = x + (size_t)id * (T_ * V_);
    float acc[V_];
#pragma unroll
    for (int j = 0; j < V_; ++j) acc[j] = 0.f;
#pragma unroll
    for (int r = 0; r < 4; ++r) {
        const float* base = p + (r * 64 + lane) * V_;
#pragma unroll
        for (int j = 0; j < V_; ++j) acc[j] += base[j];
    }
#pragma unroll
    for (int m = 32; m >= 1; m >>= 1) {
#pragma unroll
        for (int j = 0; j < V_; ++j) acc[j] += __shfl_xor(acc[j], m, 64);
    }
    if (lane == 0) {
        float* o = xsum + (size_t)id * V_;
#pragma unroll
        for (int j = 0; j < V_; ++j) o[j] = acc[j];
    }
}

// ---------- fused MFMA: y = Wc@x+bc (bf16 MFMA), out = Ycat@Acat (bf16 MFMA) ----
__global__ __launch_bounds__(256, 2) void fused_mfma(const float* __restrict__ x,
                                                     const short* __restrict__ WcB,
                                                     const float* __restrict__ bc,
                                                     const short* __restrict__ A2T,
                                                     float* __restrict__ out) {
    __shared__ __align__(16) short U[UNION_SHORTS];   // XB then (after barrier) YB
    __shared__ __align__(16) short A2l[32 * YB_STRIDE];

    const int tid  = threadIdx.x;
    const int lane = tid & 63;
    const int wv   = tid >> 6;
    const int l15  = lane & 15;
    const int q    = lane >> 4;          // quad index 0..3
    const int n    = blockIdx.x >> 6;
    const int t0   = (blockIdx.x & 63) * TCH;

    // stage A2T -> LDS (as ints)
    for (int i = tid; i < 32 * YB_STRIDE / 2; i += 256)
        ((int*)A2l)[i] = ((const int*)A2T)[i];

    // stage XB[col][c] (bf16, transposed) : coalesced global, paired bf16x2 LDS writes
    const float* xn = x + (size_t)n * (CIN_ * T_ * V_) + t0 * V_;
    for (int i = tid; i < (CIN_ / 2) * NCOLS; i += 256) {
        int col = i % NCOLS;
        int cp  = i / NCOLS;
        int c   = cp * 2;
        unsigned b0 = bf16r(xn[c * (T_ * V_) + col]);
        unsigned b1 = bf16r(xn[(c + 1) * (T_ * V_) + col]);
        *(unsigned*)&U[col * XB_STRIDE + c] = b0 | (b1 << 16);
    }

    // Wc A-fragments resident in registers: wave wv owns rows [wv*48, wv*48+48)
    short8 wfrag[3][6];
    const int rt0 = wv * 3;
    {
        const short* wb = WcB + (rt0 * 16 + l15) * CIN_ + q * 8;
#pragma unroll
        for (int j = 0; j < 3; ++j)
#pragma unroll
            for (int ks = 0; ks < 6; ++ks)
                wfrag[j][ks] = *(const short8*)(wb + j * 16 * CIN_ + ks * 32);
    }
    float4v bvec[3];
#pragma unroll
    for (int j = 0; j < 3; ++j)
        bvec[j] = *(const float4v*)(bc + (rt0 + j) * 16 + q * 4);

    __syncthreads();

    // ---- GEMM1: acc[j][ct] (16x16 tiles), K = 192 = 6*32 ----
    float4v acc[3][7];
#pragma unroll
    for (int j = 0; j < 3; ++j)
#pragma unroll
        for (int ct = 0; ct < 7; ++ct) acc[j][ct] = bvec[j];

#pragma unroll
    for (int ct = 0; ct < 7; ++ct) {
        const short* xb = &U[(ct * 16 + l15) * XB_STRIDE + q * 8];
#pragma unroll
        for (int ks = 0; ks < 6; ++ks) {
            short8 bfrag = *(const short8*)(xb + ks * 32);
#pragma unroll
            for (int j = 0; j < 3; ++j)
                acc[j][ct] = __builtin_amdgcn_mfma_f32_16x16x32_bf16(
                    wfrag[j][ks], bfrag, acc[j][ct], 0, 0, 0);
        }
    }

    __syncthreads();   // XB reads done; union region becomes YB

    // zero YB (pad cols 75..103 must be exactly 0)
    {
        int4 z = make_int4(0, 0, 0, 0);
        for (int i = tid; i < UNION_SHORTS / 8; i += 256) ((int4*)U)[i] = z;
    }
    __syncthreads();

    // write Y (bf16) into YB[(tl*64+cc)][k*25+v]
#pragma unroll
    for (int ct = 0; ct < 7; ++ct) {
        int col = ct * 16 + l15;
        if (col < NCOLS) {
            int tl = col / V_;
            int v  = col - tl * V_;
#pragma unroll
            for (int j = 0; j < 3; ++j) {
                int obase = (rt0 + j) * 16 + q * 4;
#pragma unroll
                for (int i = 0; i < 4; ++i) {
                    int o   = obase + i;
                    int row = tl * 64 + (o & 63);
                    int cY  = (o >> 6) * V_ + v;
                    U[row * YB_STRIDE + cY] = (short)bf16r(acc[j][ct][i]);
                }
            }
        }
    }
    __syncthreads();

    // ---- GEMM2: Out[(t,cc)=256][w pad 32] = Ycat[256][pad96] @ Acat ----
    short8 b2[2][3];
#pragma unroll
    for (int nt = 0; nt < 2; ++nt)
#pragma unroll
        for (int ks = 0; ks < 3; ++ks)
            b2[nt][ks] = *(const short8*)&A2l[(nt * 16 + l15) * YB_STRIDE + ks * 32 + q * 8];

    float4v o2[4][2];
#pragma unroll
    for (int mt = 0; mt < 4; ++mt)
#pragma unroll
        for (int nt = 0; nt < 2; ++nt) o2[mt][nt] = (float4v){0.f, 0.f, 0.f, 0.f};

#pragma unroll
    for (int mt = 0; mt < 4; ++mt) {
        int m = (wv * 4 + mt) * 16 + l15;
        const short* yb = &U[m * YB_STRIDE + q * 8];
#pragma unroll
        for (int ks = 0; ks < 3; ++ks) {
            short8 af = *(const short8*)(yb + ks * 32);
#pragma unroll
            for (int nt = 0; nt < 2; ++nt)
                o2[mt][nt] = __builtin_amdgcn_mfma_f32_16x16x32_bf16(
                    af, b2[nt][ks], o2[mt][nt], 0, 0, 0);
        }
    }

    // store out[n, cc, t0+tl, w]
#pragma unroll
    for (int mt = 0; mt < 4; ++mt) {
#pragma unroll
        for (int nt = 0; nt < 2; ++nt) {
            int w = nt * 16 + l15;
            if (w < V_) {
#pragma unroll
                for (int i = 0; i < 4; ++i) {
                    int m  = (wv * 4 + mt) * 16 + q * 4 + i;
                    int cc = m & 63, tl = m >> 6;
                    out[((size_t)(n * COUT_ + cc) * T_ + (t0 + tl)) * V_ + w] = o2[mt][nt][i];
                }
            }
        }
    }
}

// ---------- E1: ybar[n,o,v] = bc[o] + (1/T) * sum_c Wc[o,c] * xsum[n,c,v] -------
__global__ __launch_bounds__(256) void e1_ybar(const float* __restrict__ xsum,
                                               const float* __restrict__ Wc,
                                               const float* __restrict__ bc,
                                               float* __restrict__ ybar) {
    int i = blockIdx.x * 256 + threadIdx.x;
    if (i >= N_ * OC_ * V_) return;
    int n = i / (OC_ * V_);
    int r = i - n * (OC_ * V_);
    int o = r / V_, v = r - o * V_;
    const float* wr = Wc + o * CIN_;
    const float* xs = xsum + (size_t)n * (CIN_ * V_) + v;
    float s = 0.f;
    for (int c = 0; c < CIN_; ++c) s += wr[c] * xs[c * V_];
    ybar[i] = bc[o] + s * (1.0f / T_);
}

// ---------- E2: x1m/x2m -> sem -> graphs; block = (n, 10 j's x 25 v) ------------
__global__ __launch_bounds__(256) void e2_graphs(const float* __restrict__ ybar,
                                                 const float* __restrict__ W1,
                                                 const float* __restrict__ b1,
                                                 const float* __restrict__ W2,
                                                 const float* __restrict__ b2,
                                                 const int* __restrict__ node_type,
                                                 float* __restrict__ out) {
    __shared__ float s1[10][V_];
    __shared__ float sem[10];
    const int tid = threadIdx.x;
    const int n  = blockIdx.x >> 5;
    const int jc = blockIdx.x & 31;
    const int jl = tid / V_;
    const int v  = tid - jl * V_;
    const int j  = jc * 10 + jl;
    float x2 = 0.f;
    if (jl < 10) {
        const float* yb = ybar + (size_t)n * (OC_ * V_) + v;
        const float* w1 = W1 + j * OC_;
        const float* w2 = W2 + j * OC_;
        float a1 = b1[j], a2 = b2[j];
        for (int o = 0; o < OC_; ++o) {
            float yv = yb[o * V_];
            a1 += w1[o] * yv;
            a2 += w2[o] * yv;
        }
        s1[jl][v] = a1;
        x2 = a2;
    }
    __syncthreads();
    if (tid < 10) {
        int s = (jc * 10 + tid) >> 6;   // semantic index = j / 64
        float sum = 0.f, cnt = 0.f;
        for (int vv = 0; vv < V_; ++vv)
            if (node_type[vv] == s) { sum += s1[tid][vv]; cnt += 1.f; }
        sem[tid] = sum / cnt;
    }
    __syncthreads();
    if (jl < 10)
        out[OUT_OFF_G + (size_t)n * (SS_ * COUT_ * V_) + j * V_ + v] = sem[jl] - x2;
}

extern "C" void kernel_launch(void* const* d_in, const int* in_sizes, int n_in,
                              void* d_out, int out_size, void* d_ws, size_t ws_size,
                              hipStream_t stream) {
    const float* x         = (const float*)d_in[0];
    const float* A         = (const float*)d_in[1];
    const int*   node_type = (const int*)d_in[2];
    const float* Wc        = (const float*)d_in[3];
    const float* bc        = (const float*)d_in[4];
    const float* W1        = (const float*)d_in[5];
    const float* b1        = (const float*)d_in[6];
    const float* W2        = (const float*)d_in[7];
    const float* b2        = (const float*)d_in[8];
    float* out = (float*)d_out;

    float* xsum = (float*)d_ws;                       // 307200 floats
    float* ybar = xsum + N_ * CIN_ * V_;              // 307200 floats
    short* WcB  = (short*)(ybar + N_ * OC_ * V_);     // 36864 shorts
    short* A2T  = WcB + OC_ * CIN_;                   // 3328 shorts  (~2.42 MB total)

    hipLaunchKernelGGL(prep, dim3((OC_ * CIN_ + 255) / 256), dim3(256), 0, stream,
                       Wc, A, WcB, A2T, out);
    hipLaunchKernelGGL(reduce_x, dim3(N_ * CIN_ / 4), dim3(256), 0, stream, x, xsum);
    hipLaunchKernelGGL(fused_mfma, dim3(N_ * (T_ / TCH)), dim3(256), 0, stream,
                       x, WcB, bc, A2T, out);
    hipLaunchKernelGGL(e1_ybar, dim3((N_ * OC_ * V_ + 255) / 256), dim3(256), 0, stream,
                       xsum, Wc, bc, ybar);
    hipLaunchKernelGGL(e2_graphs, dim3(N_ * 32), dim3(256), 0, stream,
                       ybar, W1, b1, W2, b2, node_type, out);
}

// Round 3
// 662.482 us; speedup vs baseline: 2.5171x; 1.0880x over previous
//
#include <hip/hip_runtime.h>

#define N_    64
#define CIN_  192
#define T_    256
#define V_    25
#define K_    3
#define COUT_ 64
#define OC_   192
#define SS_   5

#define OUT_OFF_A (N_*COUT_*T_*V_)          // 26214400
#define OUT_OFF_G (OUT_OFF_A + K_*V_*V_)    // 26216275

#define TCH   4              // t's per inner chunk
#define HCH   2              // chunks per block -> 8 t's per block
#define NCOLS 100            // TCH*V_
#define XB_STRIDE 200        // shorts per XB row (192 + 8 pad)
#define YB_STRIDE 104        // shorts per YB row (75 -> pad 96 -> 104)
#define UNION_SHORTS 26624   // max(112*200, 256*104)
#define NYV  4800            // OC_*V_ : per-n ybar size
#define NBLK (N_*(T_/(TCH*HCH)))   // 2048 fused blocks

typedef __attribute__((ext_vector_type(8))) short short8;
typedef __attribute__((ext_vector_type(4))) float float4v;

__device__ inline unsigned bf16r(float f) {            // fp32 -> bf16 RNE
    unsigned u = __float_as_uint(f);
    return (u + 0x7fffu + ((u >> 16) & 1u)) >> 16;
}

// ---------- prep: WcB (bf16), A2T (Acat^T, bf16, zero-padded), A passthrough ----
__global__ __launch_bounds__(256) void prep(const float* __restrict__ Wc,
                                            const float* __restrict__ A,
                                            short* __restrict__ WcB,
                                            short* __restrict__ A2T,
                                            float* __restrict__ out) {
    int idx = blockIdx.x * 256 + threadIdx.x;
    if (idx < OC_ * CIN_) WcB[idx] = (short)bf16r(Wc[idx]);
    if (idx < 32 * YB_STRIDE) {           // A2T[w][kk], kk = k*25+v, zeros elsewhere
        int w = idx / YB_STRIDE, kk = idx - w * YB_STRIDE;
        short val = 0;
        if (w < V_ && kk < K_ * V_) {
            int k = kk / V_, v = kk - k * V_;
            val = (short)bf16r(A[k * V_ * V_ + v * V_ + w]);
        }
        A2T[idx] = val;
    }
    if (idx < K_ * V_ * V_) out[OUT_OFF_A + idx] = A[idx];
}

// ---------- fused MFMA: y = Wc@x+bc, out = Ycat@Acat, + per-block y t-partials --
__global__ __launch_bounds__(256, 2) void fused_mfma(const float* __restrict__ x,
                                                     const short* __restrict__ WcB,
                                                     const float* __restrict__ bc,
                                                     const short* __restrict__ A2T,
                                                     float* __restrict__ out,
                                                     float* __restrict__ part) {
    __shared__ __align__(16) short U[UNION_SHORTS];   // XB then YB, per chunk
    __shared__ __align__(16) short A2l[32 * YB_STRIDE];

    const int tid  = threadIdx.x;
    const int lane = tid & 63;
    const int wv   = tid >> 6;
    const int l15  = lane & 15;
    const int q    = lane >> 4;
    const int n    = blockIdx.x >> 5;
    const int tc   = blockIdx.x & 31;

    // stage A2T -> LDS
    for (int i = tid; i < 32 * YB_STRIDE / 2; i += 256)
        ((int*)A2l)[i] = ((const int*)A2T)[i];

    // Wc A-fragments resident in registers: wave wv owns rows [wv*48, wv*48+48)
    short8 wfrag[3][6];
    const int rt0 = wv * 3;
    {
        const short* wb = WcB + (rt0 * 16 + l15) * CIN_ + q * 8;
#pragma unroll
        for (int j = 0; j < 3; ++j)
#pragma unroll
            for (int ks = 0; ks < 6; ++ks)
                wfrag[j][ks] = *(const short8*)(wb + j * 16 * CIN_ + ks * 32);
    }
    float4v bvec[3];
#pragma unroll
    for (int j = 0; j < 3; ++j)
        bvec[j] = *(const float4v*)(bc + (rt0 + j) * 16 + q * 4);

    float racc[19];
#pragma unroll
    for (int u = 0; u < 19; ++u) racc[u] = 0.f;

    for (int h = 0; h < HCH; ++h) {
        const int t0 = tc * (TCH * HCH) + h * TCH;
        __syncthreads();   // previous chunk done with U

        // stage XB[col][c] (bf16, transposed) via float4 global loads
        const float* xn = x + (size_t)n * (CIN_ * T_ * V_) + t0 * V_;
        for (int i = tid; i < CIN_ * (NCOLS / 4); i += 256) {
            int c    = i / (NCOLS / 4);
            int col4 = i - c * (NCOLS / 4);
            float4 xv = ((const float4*)(xn + c * (T_ * V_)))[col4];
            U[(col4 * 4 + 0) * XB_STRIDE + c] = (short)bf16r(xv.x);
            U[(col4 * 4 + 1) * XB_STRIDE + c] = (short)bf16r(xv.y);
            U[(col4 * 4 + 2) * XB_STRIDE + c] = (short)bf16r(xv.z);
            U[(col4 * 4 + 3) * XB_STRIDE + c] = (short)bf16r(xv.w);
        }
        __syncthreads();

        // ---- GEMM1: acc[j][ct] (16x16 tiles), K = 192 = 6*32 ----
        float4v acc[3][7];
#pragma unroll
        for (int j = 0; j < 3; ++j)
#pragma unroll
            for (int ct = 0; ct < 7; ++ct) acc[j][ct] = bvec[j];

#pragma unroll
        for (int ct = 0; ct < 7; ++ct) {
            const short* xb = &U[(ct * 16 + l15) * XB_STRIDE + q * 8];
#pragma unroll
            for (int ks = 0; ks < 6; ++ks) {
                short8 bfrag = *(const short8*)(xb + ks * 32);
#pragma unroll
                for (int j = 0; j < 3; ++j)
                    acc[j][ct] = __builtin_amdgcn_mfma_f32_16x16x32_bf16(
                        wfrag[j][ks], bfrag, acc[j][ct], 0, 0, 0);
            }
        }
        __syncthreads();   // XB reads done; union region becomes YB

        // zero YB (pad cols must be exactly 0)
        {
            int4 z = make_int4(0, 0, 0, 0);
            for (int i = tid; i < UNION_SHORTS / 8; i += 256) ((int4*)U)[i] = z;
        }
        __syncthreads();

        // write Y (bf16) into YB[(tl*64+cc)][k*25+v]
#pragma unroll
        for (int ct = 0; ct < 7; ++ct) {
            int col = ct * 16 + l15;
            if (col < NCOLS) {
                int tl = col / V_;
                int v  = col - tl * V_;
#pragma unroll
                for (int j = 0; j < 3; ++j) {
                    int obase = (rt0 + j) * 16 + q * 4;
#pragma unroll
                    for (int i = 0; i < 4; ++i) {
                        int o   = obase + i;
                        int row = tl * 64 + (o & 63);
                        int cY  = (o >> 6) * V_ + v;
                        U[row * YB_STRIDE + cY] = (short)bf16r(acc[j][ct][i]);
                    }
                }
            }
        }
        __syncthreads();

        // ---- GEMM2: Out[(t,cc)=256][w pad 32] = Ycat[256][pad96] @ Acat ----
        short8 b2[2][3];
#pragma unroll
        for (int nt = 0; nt < 2; ++nt)
#pragma unroll
            for (int ks = 0; ks < 3; ++ks)
                b2[nt][ks] = *(const short8*)&A2l[(nt * 16 + l15) * YB_STRIDE + ks * 32 + q * 8];

        float4v o2[4][2];
#pragma unroll
        for (int mt = 0; mt < 4; ++mt)
#pragma unroll
            for (int nt = 0; nt < 2; ++nt) o2[mt][nt] = (float4v){0.f, 0.f, 0.f, 0.f};

#pragma unroll
        for (int mt = 0; mt < 4; ++mt) {
            int m = (wv * 4 + mt) * 16 + l15;
            const short* yb = &U[m * YB_STRIDE + q * 8];
#pragma unroll
            for (int ks = 0; ks < 3; ++ks) {
                short8 af = *(const short8*)(yb + ks * 32);
#pragma unroll
                for (int nt = 0; nt < 2; ++nt)
                    o2[mt][nt] = __builtin_amdgcn_mfma_f32_16x16x32_bf16(
                        af, b2[nt][ks], o2[mt][nt], 0, 0, 0);
            }
        }

        // store out[n, cc, t0+tl, w]
#pragma unroll
        for (int mt = 0; mt < 4; ++mt) {
#pragma unroll
            for (int nt = 0; nt < 2; ++nt) {
                int w = nt * 16 + l15;
                if (w < V_) {
#pragma unroll
                    for (int i = 0; i < 4; ++i) {
                        int m  = (wv * 4 + mt) * 16 + q * 4 + i;
                        int cc = m & 63, tl = m >> 6;
                        out[((size_t)(n * COUT_ + cc) * T_ + (t0 + tl)) * V_ + w] = o2[mt][nt][i];
                    }
                }
            }
        }

        // ---- y t-partials from YB: racc[u] += sum_tl y[o, tl, v] ----
#pragma unroll
        for (int u = 0; u < 19; ++u) {
            int idx = tid + u * 256;
            if (u < 18 || idx < NYV) {
                int o = idx / V_, v = idx - (idx / V_) * V_;
                int cc = o & 63, k = o >> 6;
                const short* yp = &U[cc * YB_STRIDE + k * V_ + v];
                float s = 0.f;
#pragma unroll
                for (int tl = 0; tl < TCH; ++tl) {
                    unsigned b = (unsigned short)yp[tl * 64 * YB_STRIDE];
                    s += __uint_as_float(b << 16);
                }
                racc[u] += s;
            }
        }
    }

    // flush per-block partials (coalesced)
    float* pb = part + (size_t)blockIdx.x * NYV;
#pragma unroll
    for (int u = 0; u < 19; ++u) {
        int idx = tid + u * 256;
        if (u < 18 || idx < NYV) pb[idx] = racc[u];
    }
}

// ---------- yred: ysum[n, o, v] = (1/T) * sum_tc part[n*32+tc][o,v] -------------
__global__ __launch_bounds__(256) void yred(const float* __restrict__ part,
                                            float* __restrict__ ysum) {
    int i = blockIdx.x * 256 + threadIdx.x;
    if (i >= N_ * NYV) return;
    int n = i / NYV;
    int r = i - n * NYV;
    const float* p = part + (size_t)n * 32 * NYV + r;
    float s = 0.f;
#pragma unroll
    for (int tc = 0; tc < 32; ++tc) s += p[tc * NYV];
    ysum[i] = s * (1.0f / T_);
}

// ---------- e2: x1m/x2m -> sem -> graphs; block = (n, 10 j's x 25 v) ------------
__global__ __launch_bounds__(256) void e2_graphs(const float* __restrict__ ysum,
                                                 const float* __restrict__ W1,
                                                 const float* __restrict__ b1,
                                                 const float* __restrict__ W2,
                                                 const float* __restrict__ b2,
                                                 const int* __restrict__ node_type,
                                                 float* __restrict__ out) {
    __shared__ float s1[10][V_];
    __shared__ float sem[10];
    const int tid = threadIdx.x;
    const int n  = blockIdx.x >> 5;
    const int jc = blockIdx.x & 31;
    const int jl = tid / V_;
    const int v  = tid - jl * V_;
    const int j  = jc * 10 + jl;
    float x2 = 0.f;
    if (jl < 10) {
        const float* yb = ysum + (size_t)n * NYV + v;
        const float* w1 = W1 + j * OC_;
        const float* w2 = W2 + j * OC_;
        float a1 = b1[j], a2 = b2[j];
        for (int o = 0; o < OC_; ++o) {
            float yv = yb[o * V_];
            a1 += w1[o] * yv;
            a2 += w2[o] * yv;
        }
        s1[jl][v] = a1;
        x2 = a2;
    }
    __syncthreads();
    if (tid < 10) {
        int s = (jc * 10 + tid) >> 6;   // semantic index = j / 64
        float sum = 0.f, cnt = 0.f;
        for (int vv = 0; vv < V_; ++vv)
            if (node_type[vv] == s) { sum += s1[tid][vv]; cnt += 1.f; }
        sem[tid] = sum / cnt;
    }
    __syncthreads();
    if (jl < 10)
        out[OUT_OFF_G + (size_t)n * (SS_ * COUT_ * V_) + j * V_ + v] = sem[jl] - x2;
}

extern "C" void kernel_launch(void* const* d_in, const int* in_sizes, int n_in,
                              void* d_out, int out_size, void* d_ws, size_t ws_size,
                              hipStream_t stream) {
    const float* x         = (const float*)d_in[0];
    const float* A         = (const float*)d_in[1];
    const int*   node_type = (const int*)d_in[2];
    const float* Wc        = (const float*)d_in[3];
    const float* bc        = (const float*)d_in[4];
    const float* W1        = (const float*)d_in[5];
    const float* b1        = (const float*)d_in[6];
    const float* W2        = (const float*)d_in[7];
    const float* b2        = (const float*)d_in[8];
    float* out = (float*)d_out;

    float* part = (float*)d_ws;                    // 2048*4800 floats = 39.3 MB
    float* ysum = part + (size_t)NBLK * NYV;       // 307200 floats
    short* WcB  = (short*)(ysum + N_ * NYV);       // 36864 shorts
    short* A2T  = WcB + OC_ * CIN_;                // 3328 shorts

    hipLaunchKernelGGL(prep, dim3((OC_ * CIN_ + 255) / 256), dim3(256), 0, stream,
                       Wc, A, WcB, A2T, out);
    hipLaunchKernelGGL(fused_mfma, dim3(NBLK), dim3(256), 0, stream,
                       x, WcB, bc, A2T, out, part);
    hipLaunchKernelGGL(yred, dim3((N_ * NYV + 255) / 256), dim3(256), 0, stream,
                       part, ysum);
    hipLaunchKernelGGL(e2_graphs, dim3(N_ * 32), dim3(256), 0, stream,
                       ysum, W1, b1, W2, b2, node_type, out);
}